// Round 10
// baseline (1118.802 us; speedup 1.0000x reference)
//
#include <hip/hip_runtime.h>
#include <hip/hip_bf16.h>

// ---------------------------------------------------------------------------
// TAGConv (K=2) x2 + segment-max pool + linear head. bf16 intermediates,
// fp32 accumulate, int8 row-quantized gathers for ALL props.
// Round 19: gemm<384> == gemm<256> duration (122us) across 3 structures,
// all pipes idle -> cost is per-dispatch/per-output, not K-loop. So:
// (a) STANDARD-FORM layer 2: CAT2=[X1|P X1|P^2 X1] @ W2 -- GEMM dispatches
//     5->2, quants 2->1, no Cadd inside GEMM. Needs +154MB ws; runtime
//     ws_size check with full fallback to the commuted path.
// (b) vectorized GEMM epilogue: wave-private LDS transpose (lgkmcnt(0) +
//     sched_barrier, no s_barrier) -> full-line dwordx4 stores (was
//     scalar 2B stores in every previous GEMM).
// prop_q8 untouched (at its gather-traffic roofline, 364MB @ 3.65TB/s).
// ---------------------------------------------------------------------------

typedef unsigned short u16;
typedef unsigned int u32;
typedef unsigned char u8;

__device__ inline float u2f(u16 u) { return __uint_as_float(((u32)u) << 16); }
__device__ inline u16 f2u(float f) {
    __hip_bfloat16 b = __float2bfloat16(f);
    return *reinterpret_cast<u16*>(&b);
}

// ---------------------- CSR build: counting sort ---------------------------
// NPB = 128 nodes per bucket, NC = 128 edge chunks. NB = ceil(N/NPB) <= 784.

constexpr int NPB = 128, NC = 128, NBMAX = 784;

__global__ __launch_bounds__(256) void countA_kernel(
    const int* __restrict__ dst, int* __restrict__ Hmat, int E, int CS, int NB) {
    __shared__ int hist[NBMAX];
    int tid = threadIdx.x;
    for (int b = tid; b < NB; b += 256) hist[b] = 0;
    __syncthreads();
    int base = blockIdx.x * CS;
    int end = base + CS < E ? base + CS : E;
    for (int i = base + tid; i < end; i += 256) {
        int d = __builtin_nontemporal_load(dst + i);
        atomicAdd(&hist[d >> 7], 1);
    }
    __syncthreads();
    for (int b = tid; b < NB; b += 256) Hmat[b * NC + blockIdx.x] = hist[b];
}

__global__ __launch_bounds__(256) void scatterC_kernel(
    const int* __restrict__ src, const int* __restrict__ dst,
    const int* __restrict__ Omat, uint2* __restrict__ Earr,
    int E, int CS, int NB) {
    __shared__ int cur[NBMAX];
    int tid = threadIdx.x;
    int c = blockIdx.x;
    for (int b = tid; b < NB; b += 256) cur[b] = Omat[b * NC + c];
    __syncthreads();
    int base = c * CS;
    int end = base + CS < E ? base + CS : E;
    for (int i = base + tid; i < end; i += 256) {
        int d = __builtin_nontemporal_load(dst + i);
        int s = __builtin_nontemporal_load(src + i);
        int pos = atomicAdd(&cur[d >> 7], 1);
        uint2 e;
        e.x = (u32)s;
        e.y = (u32)(d & (NPB - 1));
        Earr[pos] = e;
    }
}

// One block per bucket: local deg count -> rowptr/normv, then colidx scatter.
__global__ __launch_bounds__(256) void fineD_kernel(
    const uint2* __restrict__ Earr, const int* __restrict__ Omat,
    int* __restrict__ colidx, int* __restrict__ rowptr,
    float* __restrict__ normv, int N, int E, int NB) {
    __shared__ int cnt[NPB];
    __shared__ int scn[NPB];
    __shared__ int cur2[NPB];
    int tid = threadIdx.x;
    int b = blockIdx.x;
    int base = Omat[b * NC];
    int end = Omat[(b + 1) * NC];   // Omat[NB*NC] = E (scan tail)
    if (tid < NPB) cnt[tid] = 0;
    __syncthreads();
    for (int i = base + tid; i < end; i += 256)
        atomicAdd(&cnt[Earr[i].y], 1);
    __syncthreads();
    if (tid < NPB) scn[tid] = cnt[tid];
    __syncthreads();
    for (int off = 1; off < NPB; off <<= 1) {
        int v = (tid < NPB && tid >= off) ? scn[tid - off] : 0;
        __syncthreads();
        if (tid < NPB) scn[tid] += v;
        __syncthreads();
    }
    int node0 = b * NPB;
    if (tid < NPB) {
        int excl = scn[tid] - cnt[tid];
        cur2[tid] = base + excl;
        int node = node0 + tid;
        if (node < N) {
            rowptr[node] = base + excl;
            int d = cnt[tid];
            float fd = d < 1 ? 1.0f : (float)d;
            normv[node] = rsqrtf(fd);
        }
    }
    if (b == 0 && tid == 0) rowptr[N] = E;
    __syncthreads();
    for (int i = base + tid; i < end; i += 256) {
        uint2 e = Earr[i];
        int pos = atomicAdd(&cur2[e.y], 1);
        colidx[pos] = (int)e.x;
    }
}

// Multi-block scan.
__global__ void scan1_kernel(const int* __restrict__ in, int* __restrict__ outp,
                             int* __restrict__ bsum, int n) {
    __shared__ int sd[1024];
    int t = threadIdx.x;
    int i = blockIdx.x * 1024 + t;
    int v = (i < n) ? in[i] : 0;
    sd[t] = v;
    __syncthreads();
    for (int off = 1; off < 1024; off <<= 1) {
        int x = (t >= off) ? sd[t - off] : 0;
        __syncthreads();
        sd[t] += x;
        __syncthreads();
    }
    if (i < n) outp[i] = sd[t] - v;
    if (t == 1023) bsum[blockIdx.x] = sd[t];
}

__global__ void scan2_kernel(int* __restrict__ bsum, int nb) {
    __shared__ int sd[1024];
    int t = threadIdx.x;
    int v = (t < nb) ? bsum[t] : 0;
    sd[t] = v;
    __syncthreads();
    for (int off = 1; off < 1024; off <<= 1) {
        int x = (t >= off) ? sd[t - off] : 0;
        __syncthreads();
        sd[t] += x;
        __syncthreads();
    }
    if (t < nb) bsum[t] = sd[t] - v;
}

__global__ void scan3_kernel(int* __restrict__ outp, const int* __restrict__ bsum,
                             int n, int E) {
    int i = blockIdx.x * blockDim.x + threadIdx.x;
    if (i < n) outp[i] += bsum[i >> 10];
    if (i == 0) outp[n] = E;
}

// ------------------------------ small structs ------------------------------

struct alignas(4) U2 { u16 v[2]; };
struct alignas(8) U4 { u16 v[4]; };
struct alignas(16) U8 { u16 v[8]; };

// --------------- fused cast+quant of h (fp32 -> bf16 + biased u8) ----------
// One 64-lane group per row (128 feats): lane holds 2 floats.

__global__ __launch_bounds__(256) void castquant_f32_128(
    const float* __restrict__ h, u16* __restrict__ cat, int ldcat,
    const float* __restrict__ normv,
    u8* __restrict__ q, float* __restrict__ m, int N) {
    int row = blockIdx.x * 4 + (threadIdx.x >> 6);
    if (row >= N) return;
    int lane = threadIdx.x & 63;
    float2 f = *(const float2*)(h + (size_t)row * 128 + lane * 2);
    U2 o;
    o.v[0] = f2u(f.x);
    o.v[1] = f2u(f.y);
    *(U2*)(cat + (size_t)row * ldcat + lane * 2) = o;
    float mx = fmaxf(fabsf(f.x), fabsf(f.y));
    #pragma unroll
    for (int off = 32; off > 0; off >>= 1)
        mx = fmaxf(mx, __shfl_xor(mx, off, 64));
    float inv = mx > 0.f ? 127.f / mx : 0.f;
    u32 q0 = (u32)((int)rintf(f.x * inv) + 128);
    u32 q1 = (u32)((int)rintf(f.y * inv) + 128);
    *(unsigned short*)(q + (size_t)row * 128 + lane * 2) =
        (unsigned short)(q0 | (q1 << 8));
    if (lane == 0) m[row] = normv[row] * (mx * (1.f / 127.f));
}

// ----------- quant bf16[256] (leading dim ldx) -> biased u8 ---------------

__global__ __launch_bounds__(256) void quant_bf16_256(
    const u16* __restrict__ x, int ldx, const float* __restrict__ normv,
    u8* __restrict__ q, float* __restrict__ m, int N) {
    int row = blockIdx.x * 4 + (threadIdx.x >> 6);
    if (row >= N) return;
    int lane = threadIdx.x & 63;
    U4 v = *(const U4*)(x + (size_t)row * ldx + lane * 4);
    float f[4];
    #pragma unroll
    for (int i = 0; i < 4; ++i) f[i] = u2f(v.v[i]);
    float mx = fmaxf(fmaxf(fabsf(f[0]), fabsf(f[1])),
                     fmaxf(fabsf(f[2]), fabsf(f[3])));
    #pragma unroll
    for (int off = 32; off > 0; off >>= 1)
        mx = fmaxf(mx, __shfl_xor(mx, off, 64));
    float inv = mx > 0.f ? 127.f / mx : 0.f;
    u32 b0 = (u32)((int)rintf(f[0] * inv) + 128);
    u32 b1 = (u32)((int)rintf(f[1] * inv) + 128);
    u32 b2 = (u32)((int)rintf(f[2] * inv) + 128);
    u32 b3 = (u32)((int)rintf(f[3] * inv) + 128);
    *(u32*)(q + (size_t)row * 256 + lane * 4) =
        b0 | (b1 << 8) | (b2 << 16) | (b3 << 24);
    if (lane == 0) m[row] = normv[row] * (mx * (1.f / 127.f));
}

// ------------------------- int8 row-quantized prop -------------------------
// BPL = bytes (features) per lane; D = 32*BPL. 64-lane group per dst node,
// split into two 32-lane halves, each half processes alternate edges.
// q stored biased (+128): acc = sum nm*qb - 128*sum nm  == sum nm*q.
// Main loop: full 16-edge groups, colidx prefetched one group ahead.
// Tail: one masked clamped group. QOUT: fused re-quant of output row.

template <int BPL, int QOUT>
__global__ __launch_bounds__(256, 2) void prop_q8_kernel(
    const u8* __restrict__ qin, const float* __restrict__ m,
    u16* __restrict__ out, int ldout,
    const int* __restrict__ rowptr, const int* __restrict__ colidx,
    const float* __restrict__ normv, int N,
    u8* __restrict__ qout, float* __restrict__ mout) {
    constexpr int D = 32 * BPL;
    constexpr int NW = BPL / 4;            // u32 words per lane
    constexpr int UE = 8;                  // edges per half per group (16/group)
    int node = blockIdx.x * 4 + (threadIdx.x >> 6);
    if (node >= N) return;
    const int lane = threadIdx.x & 63;
    const int half = lane >> 5;
    const int l32 = lane & 31;
    const u32 laneoff = (u32)l32 * BPL;
    int s = rowptr[node], e = rowptr[node + 1];
    float acc[BPL];
    #pragma unroll
    for (int q = 0; q < BPL; ++q) acc[q] = 0.f;
    float msum = 0.f;
    const int nfull = (e - s) >> 4;        // full groups of 16 edges
    int p = s;
    if (nfull > 0) {
        int c[UE];
        #pragma unroll
        for (int u = 0; u < UE; ++u) c[u] = colidx[s + 2 * u + half];
        for (int g = 0; g < nfull; ++g) {
            u32 w[UE][NW];
            #pragma unroll
            for (int u = 0; u < UE; ++u) {
                u32 off = (u32)c[u] * D + laneoff;
                if (BPL == 8) {
                    uint2 gg = *(const uint2*)(qin + off);
                    w[u][0] = gg.x; w[u][1] = gg.y;
                } else {
                    w[u][0] = *(const u32*)(qin + off);
                }
            }
            float nm[UE];
            #pragma unroll
            for (int u = 0; u < UE; ++u) nm[u] = m[c[u]];
            // prefetch next group's colidx (wave-uniform branch)
            if (g + 1 < nfull) {
                int pn = s + (g + 1) * 16;
                #pragma unroll
                for (int u = 0; u < UE; ++u) c[u] = colidx[pn + 2 * u + half];
            }
            #pragma unroll
            for (int u = 0; u < UE; ++u) {
                msum += nm[u];
                #pragma unroll
                for (int t = 0; t < NW; ++t) {
                    u32 ww = w[u][t];
                    acc[4 * t + 0] += nm[u] * (float)(ww & 0xffu);
                    acc[4 * t + 1] += nm[u] * (float)((ww >> 8) & 0xffu);
                    acc[4 * t + 2] += nm[u] * (float)((ww >> 16) & 0xffu);
                    acc[4 * t + 3] += nm[u] * (float)(ww >> 24);
                }
            }
        }
        p = s + nfull * 16;
    }
    if (p < e) {
        // single masked clamped group for the tail (<16 edges)
        const int el = e - 1;
        int c[UE];
        #pragma unroll
        for (int u = 0; u < UE; ++u) {
            int idx = p + 2 * u + half;
            c[u] = colidx[idx < e ? idx : el];
        }
        u32 w[UE][NW];
        #pragma unroll
        for (int u = 0; u < UE; ++u) {
            u32 off = (u32)c[u] * D + laneoff;
            if (BPL == 8) {
                uint2 gg = *(const uint2*)(qin + off);
                w[u][0] = gg.x; w[u][1] = gg.y;
            } else {
                w[u][0] = *(const u32*)(qin + off);
            }
        }
        float nm[UE];
        #pragma unroll
        for (int u = 0; u < UE; ++u) {
            int idx = p + 2 * u + half;
            float mm = m[c[u]];
            nm[u] = idx < e ? mm : 0.f;
        }
        #pragma unroll
        for (int u = 0; u < UE; ++u) {
            msum += nm[u];
            #pragma unroll
            for (int t = 0; t < NW; ++t) {
                u32 ww = w[u][t];
                acc[4 * t + 0] += nm[u] * (float)(ww & 0xffu);
                acc[4 * t + 1] += nm[u] * (float)((ww >> 8) & 0xffu);
                acc[4 * t + 2] += nm[u] * (float)((ww >> 16) & 0xffu);
                acc[4 * t + 3] += nm[u] * (float)(ww >> 24);
            }
        }
    }
    // combine halves + bias correction + dst norm
    #pragma unroll
    for (int q = 0; q < BPL; ++q) acc[q] += __shfl_xor(acc[q], 32, 64);
    msum += __shfl_xor(msum, 32, 64);
    float nn = normv[node];
    #pragma unroll
    for (int q = 0; q < BPL; ++q) acc[q] = nn * (acc[q] - 128.f * msum);
    if (half == 0) {
        if (BPL == 8) {
            U8 o;
            #pragma unroll
            for (int q = 0; q < 8; ++q) o.v[q] = f2u(acc[q]);
            *(U8*)(out + (size_t)node * ldout + l32 * 8) = o;
        } else {
            U4 o;
            #pragma unroll
            for (int q = 0; q < 4; ++q) o.v[q] = f2u(acc[q]);
            *(U4*)(out + (size_t)node * ldout + l32 * 4) = o;
        }
    }
    if (QOUT) {
        float mx = 0.f;
        #pragma unroll
        for (int q = 0; q < BPL; ++q) mx = fmaxf(mx, fabsf(acc[q]));
        #pragma unroll
        for (int off = 16; off > 0; off >>= 1)
            mx = fmaxf(mx, __shfl_xor(mx, off, 64));
        float inv = mx > 0.f ? 127.f / mx : 0.f;
        if (half == 0) {
            u32 b[BPL > 4 ? 8 : 4];
            #pragma unroll
            for (int q = 0; q < BPL; ++q)
                b[q] = (u32)((int)rintf(acc[q] * inv) + 128);
            if (BPL == 8) {
                uint2 g;
                g.x = b[0] | (b[1] << 8) | (b[2] << 16) | (b[3] << 24);
                g.y = b[4] | (b[5] << 8) | (b[6] << 16) | (b[7] << 24);
                *(uint2*)(qout + (size_t)node * D + l32 * 8) = g;
            } else {
                *(u32*)(qout + (size_t)node * D + l32 * 4) =
                    b[0] | (b[1] << 8) | (b[2] << 16) | (b[3] << 24);
            }
            if (lane == 0) mout[node] = nn * (mx * (1.f / 127.f));
        }
    }
}

// ----------------------- barrier-free register GEMM ------------------------
// Cout[M x 256 (ld ldout)] = [relu]( A[Mpad x KK] @ Bt^T [+Cadd] [+bias] )
// One WAVE-JOB = 128 rows x 32 cols; A/B fragments straight from global
// into VGPRs; K fully unrolled; acc 64 VGPR. No barriers in main loop.
// Epilogue: wave-private LDS transpose (lgkmcnt+sched_barrier, no s_barrier)
// -> full-64B-line dwordx4 stores (prev: scalar 2B stores).
// Bijective XCD swizzle: a rowtile's 8 colgroups land on one XCD.

typedef __attribute__((ext_vector_type(8))) short bf16x8f;
typedef __attribute__((ext_vector_type(4))) float f32x4;

template <int KK>
__global__ __launch_bounds__(256, 3) void gemm_wave(
    const u16* __restrict__ A,           // [Mpad x KK]
    const u16* __restrict__ Bt,          // [256 x KK]
    const u16* __restrict__ Cadd,        // nullable, [Mpad x 256]
    const float* __restrict__ bias,      // nullable, [256]
    u16* __restrict__ Cout,              // [Mpad x ldout]
    int ldout, int M, int NJOBS, int relu) {
    __shared__ u16 st[4][128 * 32];      // 32 KB, wave-private 8KB each
    const int tid = threadIdx.x;
    const int lane = tid & 63;
    const int wave = tid >> 6;
    int nwg = gridDim.x;
    int qq = nwg >> 3, rr = nwg & 7;
    int xcd = blockIdx.x & 7, wi = blockIdx.x >> 3;
    int slot = (xcd < rr ? xcd * (qq + 1) : rr * (qq + 1) + (xcd - rr) * qq) + wi;
    int job = slot * 4 + wave;
    if (job >= NJOBS) return;
    const int rt = job >> 3;             // row tile (128 rows)
    const int cg = job & 7;              // col group (32 cols)
    const int row0 = rt << 7;
    const int col0 = cg << 5;
    const int mb = lane & 15;
    const int seg = lane >> 4;

    const u16* pA = A + (size_t)(row0 + mb) * KK + seg * 8;
    const u16* pB = Bt + (size_t)(col0 + mb) * KK + seg * 8;

    f32x4 acc[8][2];
    #pragma unroll
    for (int mi = 0; mi < 8; ++mi) {
        acc[mi][0] = (f32x4)0.f;
        acc[mi][1] = (f32x4)0.f;
    }

    #pragma unroll
    for (int j = 0; j < KK / 32; ++j) {
        bf16x8f b0 = *(const bf16x8f*)(pB + (size_t)0 * 16 * KK + j * 32);
        bf16x8f b1 = *(const bf16x8f*)(pB + (size_t)16 * KK + j * 32);
        bf16x8f a[8];
        #pragma unroll
        for (int mi = 0; mi < 8; ++mi)
            a[mi] = *(const bf16x8f*)(pA + (size_t)mi * 16 * KK + j * 32);
        #pragma unroll
        for (int mi = 0; mi < 8; ++mi) {
            acc[mi][0] = __builtin_amdgcn_mfma_f32_16x16x32_bf16(
                a[mi], b0, acc[mi][0], 0, 0, 0);
            acc[mi][1] = __builtin_amdgcn_mfma_f32_16x16x32_bf16(
                a[mi], b1, acc[mi][1], 0, 0, 0);
        }
    }

    // epilogue: C/D layout col = mb, row = seg*4 + r within each 16x16 frag.
    // Stage into wave-private LDS, then store full 64B lines.
    float bv[2];
    bv[0] = bias ? bias[col0 + 0 * 16 + mb] : 0.f;
    bv[1] = bias ? bias[col0 + 1 * 16 + mb] : 0.f;
    u16* my = st[wave];
    #pragma unroll
    for (int mi = 0; mi < 8; ++mi) {
        #pragma unroll
        for (int r = 0; r < 4; ++r) {
            int lrow = mi * 16 + seg * 4 + r;
            int grow = row0 + lrow;
            #pragma unroll
            for (int ni = 0; ni < 2; ++ni) {
                float v = acc[mi][ni][r] + bv[ni];
                if (Cadd && grow < M)
                    v += u2f(Cadd[(size_t)grow * 256 + col0 + ni * 16 + mb]);
                if (relu) v = fmaxf(v, 0.f);
                my[lrow * 32 + ni * 16 + mb] = f2u(v);
            }
        }
    }
    // wave-private RAW through LDS: drain writes, pin order (rule #18)
    asm volatile("s_waitcnt lgkmcnt(0)" ::: "memory");
    __builtin_amdgcn_sched_barrier(0);
    #pragma unroll
    for (int i = 0; i < 8; ++i) {
        int chunk = lane + 64 * i;       // 512 chunks of 16B
        int lrow = chunk >> 2;
        int co = (chunk & 3) * 8;        // u16 units
        int grow = row0 + lrow;
        if (grow < M)
            *(uint4*)(Cout + (size_t)grow * ldout + col0 + co) =
                *(const uint4*)(my + lrow * 32 + co);
    }
}

// Wt[n*K + k] = bf16(W[k*Nn + n])
__global__ void transpose_cast(const float* __restrict__ W, u16* __restrict__ Wt,
                               int K, int Nn) {
    int idx = blockIdx.x * blockDim.x + threadIdx.x;
    if (idx < K * Nn) {
        int n = idx / K, k = idx % K;
        Wt[idx] = f2u(W[(size_t)k * Nn + n]);
    }
}

// ------------------------------ pool + head --------------------------------

__global__ void pool_kernel(const u16* __restrict__ x, const int* __restrict__ gid,
                            float* __restrict__ pooled, int N, int HID) {
    int t = threadIdx.x;
    int n0 = blockIdx.x * 128;
    int n1 = n0 + 128 < N ? n0 + 128 : N;
    float cur = 0.f;
    int cg = gid[n0];
    for (int n = n0; n < n1; ++n) {
        int g = gid[n];
        if (g != cg) {
            atomicMax((int*)&pooled[(size_t)cg * HID + t], __float_as_int(cur));
            cg = g;
            cur = 0.f;
        }
        float v = u2f(x[(size_t)n * HID + t]);
        cur = cur > v ? cur : v;
    }
    atomicMax((int*)&pooled[(size_t)cg * HID + t], __float_as_int(cur));
}

__global__ void head_kernel(const float* __restrict__ pooled, const float* __restrict__ Wc,
                            const float* __restrict__ bc, float* __restrict__ out,
                            int HID, int C) {
    __shared__ float row[256];
    int g = blockIdx.x;
    int t = threadIdx.x;
    if (t < HID) row[t] = pooled[(size_t)g * HID + t];
    __syncthreads();
    if (t < C) {
        float s = bc[t];
        for (int k = 0; k < HID; ++k) s += row[k] * Wc[(size_t)k * C + t];
        out[(size_t)g * C + t] = s;
    }
}

// ------------------------------- launch ------------------------------------

extern "C" void kernel_launch(void* const* d_in, const int* in_sizes, int n_in,
                              void* d_out, int out_size, void* d_ws, size_t ws_size,
                              hipStream_t stream) {
    const float* h  = (const float*)d_in[0];
    const int* src  = (const int*)d_in[1];
    const int* dst  = (const int*)d_in[2];
    const int* gid  = (const int*)d_in[3];
    const float* W1 = (const float*)d_in[4];
    const float* b1 = (const float*)d_in[5];
    const float* W2 = (const float*)d_in[6];
    const float* b2 = (const float*)d_in[7];
    const float* Wc = (const float*)d_in[8];
    const float* bc = (const float*)d_in[9];
    float* out = (float*)d_out;

    const int N   = in_sizes[3];          // 100000
    const int E   = in_sizes[1];          // 3200000
    const int IN  = in_sizes[0] / N;      // 128
    const int HID = in_sizes[5];          // 256
    const int C   = in_sizes[9];          // 10
    const int G   = out_size / C;         // 64
    const int CAT = 3 * IN;               // 384
    const int Mpad = (N + 127) & ~127;    // 100096
    const int NB = (N + NPB - 1) / NPB;   // 782 buckets (<= NBMAX)
    const int CS = (E + NC - 1) / NC;     // 25000 edges/chunk

    char* wp = (char*)d_ws;
    auto alloc = [&](size_t bytes) {
        char* p = wp;
        wp += (bytes + 255) & ~(size_t)255;
        return p;
    };
    float* pooled = (float*)alloc((size_t)G * HID * sizeof(float));
    float* normv  = (float*)alloc((size_t)N * sizeof(float));
    float* mv     = (float*)alloc((size_t)N * sizeof(float));
    float* mv2    = (float*)alloc((size_t)N * sizeof(float));
    int* rowptr   = (int*)alloc((size_t)(N + 1) * sizeof(int));
    int* bsum     = (int*)alloc(1024 * sizeof(int));
    int* Omat     = (int*)alloc((size_t)(NB * NC + 1) * sizeof(int));
    int* Hmat     = (int*)alloc((size_t)(NB * NC) * sizeof(int));
    int* colidx   = (int*)alloc((size_t)E * sizeof(int));
    u16* Wt1      = (u16*)alloc((size_t)CAT * HID * sizeof(u16));        // [256 x 384]
    u16* Wt2      = (u16*)alloc((size_t)3 * HID * HID * sizeof(u16));    // [256 x 768]
    u16* CAT1     = (u16*)alloc((size_t)Mpad * CAT * sizeof(u16));       // [h|Ph|P2h]
    u16* X1       = (u16*)alloc((size_t)Mpad * HID * sizeof(u16));
    u16* B2       = (u16*)alloc((size_t)Mpad * HID * sizeof(u16));
    // standard-form CAT2 (optional, guarded by ws_size)
    size_t used = (size_t)(wp - (char*)d_ws);
    size_t cat2_bytes = (size_t)Mpad * 768 * sizeof(u16);
    bool bigws = (used + cat2_bytes + 256) <= ws_size;
    u16* CAT2 = bigws ? (u16*)alloc(cat2_bytes) : nullptr;

    u16* B1   = CAT1;                                  // alias (CAT1 dead then)
    uint2* Earr = (uint2*)CAT1;                        // alias (pre-cast)
    u8* Q8L2  = (u8*)(CAT1 + (size_t)Mpad * HID);      // commuted-path L2 q8
    u8* Q8A   = (u8*)B2;                               // layer-1 q8 buffers
    u8* Q8B   = (u8*)B2 + (size_t)Mpad * 128;
    u8* Q8X1  = (u8*)CAT1;                             // std-path q8 (CAT1 dead)
    u8* Q8P   = (u8*)CAT1 + (size_t)Mpad * 256;

    // --- CSR build: counting sort (no global atomics) ---
    const int n2 = NB * NC;               // 100096
    countA_kernel<<<NC, 256, 0, stream>>>(dst, Hmat, E, CS, NB);
    scan1_kernel<<<(n2 + 1023) / 1024, 1024, 0, stream>>>(Hmat, Omat, bsum, n2);
    scan2_kernel<<<1, 1024, 0, stream>>>(bsum, (n2 + 1023) / 1024);
    scan3_kernel<<<(n2 + 255) / 256, 256, 0, stream>>>(Omat, bsum, n2, E);
    scatterC_kernel<<<NC, 256, 0, stream>>>(src, dst, Omat, Earr, E, CS, NB);
    fineD_kernel<<<NB, 256, 0, stream>>>(Earr, Omat, colidx, rowptr, normv, N, E, NB);

    // --- weight transpose + bf16 cast (small) ---
    transpose_cast<<<(CAT * HID + 255) / 256, 256, 0, stream>>>(W1, Wt1, CAT, HID);
    if (bigws) {
        transpose_cast<<<(3 * HID * HID + 255) / 256, 256, 0, stream>>>(
            W2, Wt2, 3 * HID, HID);       // [256 x 768]
    } else {
        for (int s2 = 0; s2 < 3; ++s2)
            transpose_cast<<<(HID * HID + 255) / 256, 256, 0, stream>>>(
                W2 + (size_t)s2 * HID * HID, Wt2 + (size_t)s2 * HID * HID, HID, HID);
    }

    // --- layer 1: CAT1 = [bf16(h) | P h | P^2 h]; X1 = relu(CAT1@W1+b1) ---
    int pb = (N + 3) / 4;
    castquant_f32_128<<<pb, 256, 0, stream>>>(h, CAT1, CAT, normv, Q8A, mv, N);
    prop_q8_kernel<4, 1><<<pb, 256, 0, stream>>>(Q8A, mv, CAT1 + IN, CAT,
                                                 rowptr, colidx, normv, N, Q8B, mv2);
    prop_q8_kernel<4, 0><<<pb, 256, 0, stream>>>(Q8B, mv2, CAT1 + 2 * IN, CAT,
                                                 rowptr, colidx, normv, N,
                                                 nullptr, nullptr);
    const int NJOBS = (Mpad / 128) * 8;   // 6256 wave-jobs
    const int GW = NJOBS / 4;             // 1564 blocks (4 waves each)

    if (bigws) {
        // ---- standard form: CAT2 = [X1 | P X1 | P^2 X1]; X2 = CAT2@W2 ----
        gemm_wave<384><<<GW, 256, 0, stream>>>(CAT1, Wt1, nullptr, b1,
                                               CAT2, 768, N, NJOBS, 1);
        quant_bf16_256<<<pb, 256, 0, stream>>>(CAT2, 768, normv, Q8X1, mv, N);
        prop_q8_kernel<8, 1><<<pb, 256, 0, stream>>>(Q8X1, mv, CAT2 + 256, 768,
                                                     rowptr, colidx, normv, N,
                                                     Q8P, mv2);
        prop_q8_kernel<8, 0><<<pb, 256, 0, stream>>>(Q8P, mv2, CAT2 + 512, 768,
                                                     rowptr, colidx, normv, N,
                                                     nullptr, nullptr);
        u16* X2 = (u16*)CAT1;             // CAT1/Q8 regions dead now
        gemm_wave<768><<<GW, 256, 0, stream>>>(CAT2, Wt2, nullptr, b2,
                                               X2, 256, N, NJOBS, 1);
        hipMemsetAsync(pooled, 0, (size_t)G * HID * sizeof(float), stream);
        pool_kernel<<<(N + 127) / 128, HID, 0, stream>>>(X2, gid, pooled, N, HID);
    } else {
        // ---- fallback: commuted layer 2 (R9 behavior) ----
        gemm_wave<384><<<GW, 256, 0, stream>>>(CAT1, Wt1, nullptr, b1,
                                               X1, 256, N, NJOBS, 1);
        gemm_wave<256><<<GW, 256, 0, stream>>>(X1, Wt2 + (size_t)2 * HID * HID,
                                               nullptr, nullptr, B1, 256, N, NJOBS, 0);
        quant_bf16_256<<<pb, 256, 0, stream>>>(B1, 256, normv, Q8L2, mv, N);
        prop_q8_kernel<8, 0><<<pb, 256, 0, stream>>>(Q8L2, mv, B2, HID,
                                                     rowptr, colidx, normv, N,
                                                     nullptr, nullptr);
        gemm_wave<256><<<GW, 256, 0, stream>>>(X1, Wt2 + (size_t)HID * HID,
                                               B2, nullptr, B1, 256, N, NJOBS, 0);
        quant_bf16_256<<<pb, 256, 0, stream>>>(B1, 256, normv, Q8L2, mv, N);
        prop_q8_kernel<8, 0><<<pb, 256, 0, stream>>>(Q8L2, mv, B2, HID,
                                                     rowptr, colidx, normv, N,
                                                     nullptr, nullptr);
        gemm_wave<256><<<GW, 256, 0, stream>>>(X1, Wt2, B2, b2, B1, 256, N, NJOBS, 1);
        hipMemsetAsync(pooled, 0, (size_t)G * HID * sizeof(float), stream);
        pool_kernel<<<(N + 127) / 128, HID, 0, stream>>>(B1, gid, pooled, N, HID);
    }

    head_kernel<<<G, HID, 0, stream>>>(pooled, Wc, bc, out, HID, C);
}

// Round 11
// 1063.641 us; speedup vs baseline: 1.0519x; 1.0519x over previous
//
#include <hip/hip_runtime.h>
#include <hip/hip_bf16.h>

// ---------------------------------------------------------------------------
// TAGConv (K=2) x2 + segment-max pool + linear head. bf16 intermediates,
// fp32 accumulate, int8 row-quantized gathers for ALL props. Layer-2
// commuted: X2 = X1@W2a + P(X1@W2b + P(X1@W2c)).
// Round 20: R10's ws-gated standard form never ran (fallback: 5 identical
// gemm rows in top-5); LDS epilogue was -9us (800K bank conflicts) ->
// reverted. This round reduces gemm dispatches 5->3 and kills both quant
// dispatches WITHIN the proven ~195MB footprint:
//  - gemmq: 16row x 256col wave-jobs, per-row absmax via shfl_xor (wave-
//    local) -> writes q8(X1@W2c)+scales directly (quant fused, f32 source).
//  - gemmd: ONE dual-output dispatch for Yb=X1@W2b and Ya=X1@W2a (16
//    colgroups/rowtile). Discriminator: ~130us => per-dispatch floor.
//  - prop gets fused Cadd/bias/relu: d3 = q8(Yb + P(q8c)); d4 =
//    relu(Ya + P(q8d) + b2). No separate quant, no Cadd inside GEMMs.
// Aliases: Q8c/Yb <- dead CAT1, Ya <- dead B2, Q8d <- dead X1, X2 <- CAT1.
// ---------------------------------------------------------------------------

typedef unsigned short u16;
typedef unsigned int u32;
typedef unsigned char u8;

__device__ inline float u2f(u16 u) { return __uint_as_float(((u32)u) << 16); }
__device__ inline u16 f2u(float f) {
    __hip_bfloat16 b = __float2bfloat16(f);
    return *reinterpret_cast<u16*>(&b);
}

// ---------------------- CSR build: counting sort ---------------------------
// NPB = 128 nodes per bucket, NC = 128 edge chunks. NB = ceil(N/NPB) <= 784.

constexpr int NPB = 128, NC = 128, NBMAX = 784;

__global__ __launch_bounds__(256) void countA_kernel(
    const int* __restrict__ dst, int* __restrict__ Hmat, int E, int CS, int NB) {
    __shared__ int hist[NBMAX];
    int tid = threadIdx.x;
    for (int b = tid; b < NB; b += 256) hist[b] = 0;
    __syncthreads();
    int base = blockIdx.x * CS;
    int end = base + CS < E ? base + CS : E;
    for (int i = base + tid; i < end; i += 256) {
        int d = __builtin_nontemporal_load(dst + i);
        atomicAdd(&hist[d >> 7], 1);
    }
    __syncthreads();
    for (int b = tid; b < NB; b += 256) Hmat[b * NC + blockIdx.x] = hist[b];
}

__global__ __launch_bounds__(256) void scatterC_kernel(
    const int* __restrict__ src, const int* __restrict__ dst,
    const int* __restrict__ Omat, uint2* __restrict__ Earr,
    int E, int CS, int NB) {
    __shared__ int cur[NBMAX];
    int tid = threadIdx.x;
    int c = blockIdx.x;
    for (int b = tid; b < NB; b += 256) cur[b] = Omat[b * NC + c];
    __syncthreads();
    int base = c * CS;
    int end = base + CS < E ? base + CS : E;
    for (int i = base + tid; i < end; i += 256) {
        int d = __builtin_nontemporal_load(dst + i);
        int s = __builtin_nontemporal_load(src + i);
        int pos = atomicAdd(&cur[d >> 7], 1);
        uint2 e;
        e.x = (u32)s;
        e.y = (u32)(d & (NPB - 1));
        Earr[pos] = e;
    }
}

// One block per bucket: local deg count -> rowptr/normv, then colidx scatter.
__global__ __launch_bounds__(256) void fineD_kernel(
    const uint2* __restrict__ Earr, const int* __restrict__ Omat,
    int* __restrict__ colidx, int* __restrict__ rowptr,
    float* __restrict__ normv, int N, int E, int NB) {
    __shared__ int cnt[NPB];
    __shared__ int scn[NPB];
    __shared__ int cur2[NPB];
    int tid = threadIdx.x;
    int b = blockIdx.x;
    int base = Omat[b * NC];
    int end = Omat[(b + 1) * NC];   // Omat[NB*NC] = E (scan tail)
    if (tid < NPB) cnt[tid] = 0;
    __syncthreads();
    for (int i = base + tid; i < end; i += 256)
        atomicAdd(&cnt[Earr[i].y], 1);
    __syncthreads();
    if (tid < NPB) scn[tid] = cnt[tid];
    __syncthreads();
    for (int off = 1; off < NPB; off <<= 1) {
        int v = (tid < NPB && tid >= off) ? scn[tid - off] : 0;
        __syncthreads();
        if (tid < NPB) scn[tid] += v;
        __syncthreads();
    }
    int node0 = b * NPB;
    if (tid < NPB) {
        int excl = scn[tid] - cnt[tid];
        cur2[tid] = base + excl;
        int node = node0 + tid;
        if (node < N) {
            rowptr[node] = base + excl;
            int d = cnt[tid];
            float fd = d < 1 ? 1.0f : (float)d;
            normv[node] = rsqrtf(fd);
        }
    }
    if (b == 0 && tid == 0) rowptr[N] = E;
    __syncthreads();
    for (int i = base + tid; i < end; i += 256) {
        uint2 e = Earr[i];
        int pos = atomicAdd(&cur2[e.y], 1);
        colidx[pos] = (int)e.x;
    }
}

// Multi-block scan.
__global__ void scan1_kernel(const int* __restrict__ in, int* __restrict__ outp,
                             int* __restrict__ bsum, int n) {
    __shared__ int sd[1024];
    int t = threadIdx.x;
    int i = blockIdx.x * 1024 + t;
    int v = (i < n) ? in[i] : 0;
    sd[t] = v;
    __syncthreads();
    for (int off = 1; off < 1024; off <<= 1) {
        int x = (t >= off) ? sd[t - off] : 0;
        __syncthreads();
        sd[t] += x;
        __syncthreads();
    }
    if (i < n) outp[i] = sd[t] - v;
    if (t == 1023) bsum[blockIdx.x] = sd[t];
}

__global__ void scan2_kernel(int* __restrict__ bsum, int nb) {
    __shared__ int sd[1024];
    int t = threadIdx.x;
    int v = (t < nb) ? bsum[t] : 0;
    sd[t] = v;
    __syncthreads();
    for (int off = 1; off < 1024; off <<= 1) {
        int x = (t >= off) ? sd[t - off] : 0;
        __syncthreads();
        sd[t] += x;
        __syncthreads();
    }
    if (t < nb) bsum[t] = sd[t] - v;
}

__global__ void scan3_kernel(int* __restrict__ outp, const int* __restrict__ bsum,
                             int n, int E) {
    int i = blockIdx.x * blockDim.x + threadIdx.x;
    if (i < n) outp[i] += bsum[i >> 10];
    if (i == 0) outp[n] = E;
}

// ------------------------------ small structs ------------------------------

struct alignas(4) U2 { u16 v[2]; };
struct alignas(8) U4 { u16 v[4]; };
struct alignas(16) U8 { u16 v[8]; };

// --------------- fused cast+quant of h (fp32 -> bf16 + biased u8) ----------

__global__ __launch_bounds__(256) void castquant_f32_128(
    const float* __restrict__ h, u16* __restrict__ cat, int ldcat,
    const float* __restrict__ normv,
    u8* __restrict__ q, float* __restrict__ m, int N) {
    int row = blockIdx.x * 4 + (threadIdx.x >> 6);
    if (row >= N) return;
    int lane = threadIdx.x & 63;
    float2 f = *(const float2*)(h + (size_t)row * 128 + lane * 2);
    U2 o;
    o.v[0] = f2u(f.x);
    o.v[1] = f2u(f.y);
    *(U2*)(cat + (size_t)row * ldcat + lane * 2) = o;
    float mx = fmaxf(fabsf(f.x), fabsf(f.y));
    #pragma unroll
    for (int off = 32; off > 0; off >>= 1)
        mx = fmaxf(mx, __shfl_xor(mx, off, 64));
    float inv = mx > 0.f ? 127.f / mx : 0.f;
    u32 q0 = (u32)((int)rintf(f.x * inv) + 128);
    u32 q1 = (u32)((int)rintf(f.y * inv) + 128);
    *(unsigned short*)(q + (size_t)row * 128 + lane * 2) =
        (unsigned short)(q0 | (q1 << 8));
    if (lane == 0) m[row] = normv[row] * (mx * (1.f / 127.f));
}

// ------------------------- int8 row-quantized prop -------------------------
// BPL bytes/lane; D = 32*BPL. 64-lane group per dst node, two 32-lane
// halves on alternate edges. q biased (+128). Fused epilogue:
//   v = nn*(acc - 128*msum) [+ cadd(bf16,[N x 256])] [+ bias] [relu]
//   WB: write bf16 v;  QOUT: per-row requant of v -> qout (+ mout).

template <int BPL, int QOUT, int WB, int CADD>
__global__ __launch_bounds__(256, 2) void prop_q8_kernel(
    const u8* __restrict__ qin, const float* __restrict__ m,
    u16* __restrict__ out, int ldout,
    const int* __restrict__ rowptr, const int* __restrict__ colidx,
    const float* __restrict__ normv, int N,
    const u16* __restrict__ cadd, const float* __restrict__ bias, int relu,
    u8* __restrict__ qout, float* __restrict__ mout) {
    constexpr int D = 32 * BPL;
    constexpr int NW = BPL / 4;            // u32 words per lane
    constexpr int UE = 8;                  // edges per half per group (16/group)
    int node = blockIdx.x * 4 + (threadIdx.x >> 6);
    if (node >= N) return;
    const int lane = threadIdx.x & 63;
    const int half = lane >> 5;
    const int l32 = lane & 31;
    const u32 laneoff = (u32)l32 * BPL;
    int s = rowptr[node], e = rowptr[node + 1];
    float acc[BPL];
    #pragma unroll
    for (int q = 0; q < BPL; ++q) acc[q] = 0.f;
    float msum = 0.f;
    const int nfull = (e - s) >> 4;        // full groups of 16 edges
    int p = s;
    if (nfull > 0) {
        int c[UE];
        #pragma unroll
        for (int u = 0; u < UE; ++u) c[u] = colidx[s + 2 * u + half];
        for (int g = 0; g < nfull; ++g) {
            u32 w[UE][NW];
            #pragma unroll
            for (int u = 0; u < UE; ++u) {
                u32 off = (u32)c[u] * D + laneoff;
                if (BPL == 8) {
                    uint2 gg = *(const uint2*)(qin + off);
                    w[u][0] = gg.x; w[u][1] = gg.y;
                } else {
                    w[u][0] = *(const u32*)(qin + off);
                }
            }
            float nm[UE];
            #pragma unroll
            for (int u = 0; u < UE; ++u) nm[u] = m[c[u]];
            if (g + 1 < nfull) {
                int pn = s + (g + 1) * 16;
                #pragma unroll
                for (int u = 0; u < UE; ++u) c[u] = colidx[pn + 2 * u + half];
            }
            #pragma unroll
            for (int u = 0; u < UE; ++u) {
                msum += nm[u];
                #pragma unroll
                for (int t = 0; t < NW; ++t) {
                    u32 ww = w[u][t];
                    acc[4 * t + 0] += nm[u] * (float)(ww & 0xffu);
                    acc[4 * t + 1] += nm[u] * (float)((ww >> 8) & 0xffu);
                    acc[4 * t + 2] += nm[u] * (float)((ww >> 16) & 0xffu);
                    acc[4 * t + 3] += nm[u] * (float)(ww >> 24);
                }
            }
        }
        p = s + nfull * 16;
    }
    if (p < e) {
        const int el = e - 1;
        int c[UE];
        #pragma unroll
        for (int u = 0; u < UE; ++u) {
            int idx = p + 2 * u + half;
            c[u] = colidx[idx < e ? idx : el];
        }
        u32 w[UE][NW];
        #pragma unroll
        for (int u = 0; u < UE; ++u) {
            u32 off = (u32)c[u] * D + laneoff;
            if (BPL == 8) {
                uint2 gg = *(const uint2*)(qin + off);
                w[u][0] = gg.x; w[u][1] = gg.y;
            } else {
                w[u][0] = *(const u32*)(qin + off);
            }
        }
        float nm[UE];
        #pragma unroll
        for (int u = 0; u < UE; ++u) {
            int idx = p + 2 * u + half;
            float mm = m[c[u]];
            nm[u] = idx < e ? mm : 0.f;
        }
        #pragma unroll
        for (int u = 0; u < UE; ++u) {
            msum += nm[u];
            #pragma unroll
            for (int t = 0; t < NW; ++t) {
                u32 ww = w[u][t];
                acc[4 * t + 0] += nm[u] * (float)(ww & 0xffu);
                acc[4 * t + 1] += nm[u] * (float)((ww >> 8) & 0xffu);
                acc[4 * t + 2] += nm[u] * (float)((ww >> 16) & 0xffu);
                acc[4 * t + 3] += nm[u] * (float)(ww >> 24);
            }
        }
    }
    // combine halves + bias correction + dst norm
    #pragma unroll
    for (int q = 0; q < BPL; ++q) acc[q] += __shfl_xor(acc[q], 32, 64);
    msum += __shfl_xor(msum, 32, 64);
    float nn = normv[node];
    float v[BPL];
    #pragma unroll
    for (int q = 0; q < BPL; ++q) v[q] = nn * (acc[q] - 128.f * msum);
    if (CADD) {
        if (BPL == 8) {
            U8 cv = *(const U8*)(cadd + (size_t)node * 256 + l32 * 8);
            #pragma unroll
            for (int q = 0; q < 8; ++q) v[q] += u2f(cv.v[q]);
        } else {
            U4 cv = *(const U4*)(cadd + (size_t)node * 256 + l32 * 4);
            #pragma unroll
            for (int q = 0; q < 4; ++q) v[q] += u2f(cv.v[q]);
        }
    }
    if (bias) {
        #pragma unroll
        for (int q = 0; q < BPL; ++q) v[q] += bias[l32 * BPL + q];
    }
    if (relu) {
        #pragma unroll
        for (int q = 0; q < BPL; ++q) v[q] = fmaxf(v[q], 0.f);
    }
    if (WB && half == 0) {
        if (BPL == 8) {
            U8 o;
            #pragma unroll
            for (int q = 0; q < 8; ++q) o.v[q] = f2u(v[q]);
            *(U8*)(out + (size_t)node * ldout + l32 * 8) = o;
        } else {
            U4 o;
            #pragma unroll
            for (int q = 0; q < 4; ++q) o.v[q] = f2u(v[q]);
            *(U4*)(out + (size_t)node * ldout + l32 * 4) = o;
        }
    }
    if (QOUT) {
        float mx = 0.f;
        #pragma unroll
        for (int q = 0; q < BPL; ++q) mx = fmaxf(mx, fabsf(v[q]));
        #pragma unroll
        for (int off = 16; off > 0; off >>= 1)
            mx = fmaxf(mx, __shfl_xor(mx, off, 64));
        float inv = mx > 0.f ? 127.f / mx : 0.f;
        if (half == 0) {
            u32 b[BPL > 4 ? 8 : 4];
            #pragma unroll
            for (int q = 0; q < BPL; ++q)
                b[q] = (u32)((int)rintf(v[q] * inv) + 128);
            if (BPL == 8) {
                uint2 g;
                g.x = b[0] | (b[1] << 8) | (b[2] << 16) | (b[3] << 24);
                g.y = b[4] | (b[5] << 8) | (b[6] << 16) | (b[7] << 24);
                *(uint2*)(qout + (size_t)node * D + l32 * 8) = g;
            } else {
                *(u32*)(qout + (size_t)node * D + l32 * 4) =
                    b[0] | (b[1] << 8) | (b[2] << 16) | (b[3] << 24);
            }
            if (lane == 0) mout[node] = nn * (mx * (1.f / 127.f));
        }
    }
}

// ----------------------- barrier-free register GEMM ------------------------
// One WAVE-JOB = 128 rows x 32 cols; A/B fragments straight from global to
// VGPRs; K fully unrolled; direct stores (R9 epilogue). DUAL=1: 16 col-
// groups/rowtile, cg<8 -> C0 with B at Bt+256 (W2b^T), cg>=8 -> C1 with
// B at Bt (W2a^T); B row pitch ldb.

typedef __attribute__((ext_vector_type(8))) short bf16x8f;
typedef __attribute__((ext_vector_type(4))) float f32x4;

template <int KK, int DUAL>
__global__ __launch_bounds__(256, 3) void gemm_wave(
    const u16* __restrict__ A,           // [Mpad x KK]
    const u16* __restrict__ Bt, int ldb, // rows = out cols, pitch ldb
    const float* __restrict__ bias,      // nullable, [256]
    u16* __restrict__ C0, u16* __restrict__ C1,
    int M, int NJOBS, int relu) {
    const int tid = threadIdx.x;
    const int lane = tid & 63;
    const int wave = tid >> 6;
    int nwg = gridDim.x;
    int qq = nwg >> 3, rr = nwg & 7;
    int xcd = blockIdx.x & 7, wi = blockIdx.x >> 3;
    int slot = (xcd < rr ? xcd * (qq + 1) : rr * (qq + 1) + (xcd - rr) * qq) + wi;
    int job = slot * 4 + wave;
    if (job >= NJOBS) return;
    const int cg = DUAL ? (job & 15) : (job & 7);
    const int rt = DUAL ? (job >> 4) : (job >> 3);
    const int row0 = rt << 7;
    const int col0 = (DUAL ? (cg & 7) : cg) << 5;
    const u16* bb = DUAL ? (cg < 8 ? Bt + 256 : Bt) : Bt;
    u16* Cout = DUAL ? (cg < 8 ? C0 : C1) : C0;
    const int mb = lane & 15;
    const int seg = lane >> 4;

    const u16* pA = A + (size_t)(row0 + mb) * KK + seg * 8;
    const u16* pB = bb + (size_t)(col0 + mb) * ldb + seg * 8;

    f32x4 acc[8][2];
    #pragma unroll
    for (int mi = 0; mi < 8; ++mi) {
        acc[mi][0] = (f32x4)0.f;
        acc[mi][1] = (f32x4)0.f;
    }

    #pragma unroll
    for (int j = 0; j < KK / 32; ++j) {
        bf16x8f b0 = *(const bf16x8f*)(pB + (size_t)j * 32);
        bf16x8f b1 = *(const bf16x8f*)(pB + (size_t)16 * ldb + j * 32);
        bf16x8f a[8];
        #pragma unroll
        for (int mi = 0; mi < 8; ++mi)
            a[mi] = *(const bf16x8f*)(pA + (size_t)mi * 16 * KK + j * 32);
        #pragma unroll
        for (int mi = 0; mi < 8; ++mi) {
            acc[mi][0] = __builtin_amdgcn_mfma_f32_16x16x32_bf16(
                a[mi], b0, acc[mi][0], 0, 0, 0);
            acc[mi][1] = __builtin_amdgcn_mfma_f32_16x16x32_bf16(
                a[mi], b1, acc[mi][1], 0, 0, 0);
        }
    }

    // epilogue: C/D layout col = mb, row = seg*4 + r within 16x16 frag
    float bv[2];
    bv[0] = bias ? bias[col0 + mb] : 0.f;
    bv[1] = bias ? bias[col0 + 16 + mb] : 0.f;
    #pragma unroll
    for (int mi = 0; mi < 8; ++mi) {
        #pragma unroll
        for (int r = 0; r < 4; ++r) {
            int row = row0 + mi * 16 + seg * 4 + r;
            if (row < M) {
                #pragma unroll
                for (int ni = 0; ni < 2; ++ni) {
                    float v = acc[mi][ni][r] + bv[ni];
                    if (relu) v = fmaxf(v, 0.f);
                    Cout[(size_t)row * 256 + col0 + ni * 16 + mb] = f2u(v);
                }
            }
        }
    }
}

// -------------- quantizing GEMM: q8(A @ Bt^T) with per-ROW scale -----------
// One WAVE-JOB = 16 rows x 256 cols (acc[16] f32x4 = 64 VGPR). Per-row
// absmax: reduce over 16 regs + shfl_xor over the 16-lane mb group ->
// wave-local per-row scale (same granularity as the old quant kernel,
// but quantizing from f32). Bytes staged via wave-private LDS (pitch 272
// = 17x16B, conflict-light), then full 16B-line stores.

template <int KK>
__global__ __launch_bounds__(256, 2) void gemmq_wave(
    const u16* __restrict__ A,           // [Mpad x KK]
    const u16* __restrict__ Bt, int ldb, // rows = out cols (256), pitch ldb
    u8* __restrict__ Qout,               // [Mpad x 256] biased u8
    float* __restrict__ mout,            // [Mpad]
    const float* __restrict__ normv,
    int M, int NJOBS) {
    __shared__ u8 st[4][16 * 272];
    const int tid = threadIdx.x;
    const int lane = tid & 63;
    const int wave = tid >> 6;
    int nwg = gridDim.x;
    int qq = nwg >> 3, rr = nwg & 7;
    int xcd = blockIdx.x & 7, wi = blockIdx.x >> 3;
    int slot = (xcd < rr ? xcd * (qq + 1) : rr * (qq + 1) + (xcd - rr) * qq) + wi;
    int job = slot * 4 + wave;
    if (job >= NJOBS) return;
    const int row0 = job << 4;           // 16 rows per job
    const int mb = lane & 15;
    const int seg = lane >> 4;

    const u16* pA = A + (size_t)(row0 + mb) * KK + seg * 8;
    const u16* pB = Bt + (size_t)mb * ldb + seg * 8;

    f32x4 acc[16];
    #pragma unroll
    for (int ni = 0; ni < 16; ++ni) acc[ni] = (f32x4)0.f;

    #pragma unroll
    for (int j = 0; j < KK / 32; ++j) {
        bf16x8f a = *(const bf16x8f*)(pA + (size_t)j * 32);
        #pragma unroll
        for (int g = 0; g < 2; ++g) {
            bf16x8f b[8];
            #pragma unroll
            for (int t = 0; t < 8; ++t)
                b[t] = *(const bf16x8f*)(pB + (size_t)((g * 8 + t) * 16) * ldb
                                         + j * 32);
            #pragma unroll
            for (int t = 0; t < 8; ++t)
                acc[g * 8 + t] = __builtin_amdgcn_mfma_f32_16x16x32_bf16(
                    a, b[t], acc[g * 8 + t], 0, 0, 0);
        }
    }

    // per-row quant: row = seg*4 + r; cols = ni*16 + mb
    u8* my = st[wave];
    #pragma unroll
    for (int r = 0; r < 4; ++r) {
        int lrow = seg * 4 + r;
        float mx = 0.f;
        #pragma unroll
        for (int ni = 0; ni < 16; ++ni) mx = fmaxf(mx, fabsf(acc[ni][r]));
        #pragma unroll
        for (int off = 1; off < 16; off <<= 1)
            mx = fmaxf(mx, __shfl_xor(mx, off, 64));
        float inv = mx > 0.f ? 127.f / mx : 0.f;
        #pragma unroll
        for (int ni = 0; ni < 16; ++ni)
            my[lrow * 272 + ni * 16 + mb] =
                (u8)((int)rintf(acc[ni][r] * inv) + 128);
        int grow = row0 + lrow;
        if (mb == 0 && grow < M)
            mout[grow] = normv[grow] * (mx * (1.f / 127.f));
    }
    asm volatile("s_waitcnt lgkmcnt(0)" ::: "memory");
    __builtin_amdgcn_sched_barrier(0);
    #pragma unroll
    for (int i = 0; i < 4; ++i) {
        int chunk = lane + 64 * i;       // 256 chunks of 16B
        int lrow = chunk >> 4;
        int co = chunk & 15;
        int grow = row0 + lrow;
        if (grow < M)
            *(uint4*)(Qout + (size_t)grow * 256 + co * 16) =
                *(const uint4*)(my + lrow * 272 + co * 16);
    }
}

// Wt[n*K + k] = bf16(W[k*Nn + n])
__global__ void transpose_cast(const float* __restrict__ W, u16* __restrict__ Wt,
                               int K, int Nn) {
    int idx = blockIdx.x * blockDim.x + threadIdx.x;
    if (idx < K * Nn) {
        int n = idx / K, k = idx % K;
        Wt[idx] = f2u(W[(size_t)k * Nn + n]);
    }
}

// ------------------------------ pool + head --------------------------------

__global__ void pool_kernel(const u16* __restrict__ x, const int* __restrict__ gid,
                            float* __restrict__ pooled, int N, int HID) {
    int t = threadIdx.x;
    int n0 = blockIdx.x * 128;
    int n1 = n0 + 128 < N ? n0 + 128 : N;
    float cur = 0.f;
    int cg = gid[n0];
    for (int n = n0; n < n1; ++n) {
        int g = gid[n];
        if (g != cg) {
            atomicMax((int*)&pooled[(size_t)cg * HID + t], __float_as_int(cur));
            cg = g;
            cur = 0.f;
        }
        float v = u2f(x[(size_t)n * HID + t]);
        cur = cur > v ? cur : v;
    }
    atomicMax((int*)&pooled[(size_t)cg * HID + t], __float_as_int(cur));
}

__global__ void head_kernel(const float* __restrict__ pooled, const float* __restrict__ Wc,
                            const float* __restrict__ bc, float* __restrict__ out,
                            int HID, int C) {
    __shared__ float row[256];
    int g = blockIdx.x;
    int t = threadIdx.x;
    if (t < HID) row[t] = pooled[(size_t)g * HID + t];
    __syncthreads();
    if (t < C) {
        float s = bc[t];
        for (int k = 0; k < HID; ++k) s += row[k] * Wc[(size_t)k * C + t];
        out[(size_t)g * C + t] = s;
    }
}

// ------------------------------- launch ------------------------------------

extern "C" void kernel_launch(void* const* d_in, const int* in_sizes, int n_in,
                              void* d_out, int out_size, void* d_ws, size_t ws_size,
                              hipStream_t stream) {
    const float* h  = (const float*)d_in[0];
    const int* src  = (const int*)d_in[1];
    const int* dst  = (const int*)d_in[2];
    const int* gid  = (const int*)d_in[3];
    const float* W1 = (const float*)d_in[4];
    const float* b1 = (const float*)d_in[5];
    const float* W2 = (const float*)d_in[6];
    const float* b2 = (const float*)d_in[7];
    const float* Wc = (const float*)d_in[8];
    const float* bc = (const float*)d_in[9];
    float* out = (float*)d_out;

    const int N   = in_sizes[3];          // 100000
    const int E   = in_sizes[1];          // 3200000
    const int IN  = in_sizes[0] / N;      // 128
    const int HID = in_sizes[5];          // 256
    const int C   = in_sizes[9];          // 10
    const int G   = out_size / C;         // 64
    const int CAT = 3 * IN;               // 384
    const int Mpad = (N + 127) & ~127;    // 100096
    const int NB = (N + NPB - 1) / NPB;   // 782 buckets (<= NBMAX)
    const int CS = (E + NC - 1) / NC;     // 25000 edges/chunk

    char* wp = (char*)d_ws;
    auto alloc = [&](size_t bytes) {
        char* p = wp;
        wp += (bytes + 255) & ~(size_t)255;
        return p;
    };
    float* pooled = (float*)alloc((size_t)G * HID * sizeof(float));
    float* normv  = (float*)alloc((size_t)N * sizeof(float));
    float* mv     = (float*)alloc((size_t)N * sizeof(float));
    float* mv2    = (float*)alloc((size_t)N * sizeof(float));
    float* mvq    = (float*)alloc((size_t)N * sizeof(float));
    int* rowptr   = (int*)alloc((size_t)(N + 1) * sizeof(int));
    int* bsum     = (int*)alloc(1024 * sizeof(int));
    int* Omat     = (int*)alloc((size_t)(NB * NC + 1) * sizeof(int));
    int* Hmat     = (int*)alloc((size_t)(NB * NC) * sizeof(int));
    int* colidx   = (int*)alloc((size_t)E * sizeof(int));
    u16* Wt1      = (u16*)alloc((size_t)CAT * HID * sizeof(u16));        // [256 x 384]
    u16* Wt2f     = (u16*)alloc((size_t)3 * HID * HID * sizeof(u16));    // [256 x 768]
    u16* X1       = (u16*)alloc((size_t)Mpad * 256 * sizeof(u16));       // 51MB
    u16* CAT1     = (u16*)alloc((size_t)Mpad * 384 * sizeof(u16));       // 77MB
    u16* B2      = (u16*)alloc((size_t)Mpad * 256 * sizeof(u16));        // 51MB

    // aliases (lifetimes verified):
    uint2* Earr = (uint2*)CAT1;                        // pre-cast only
    u8* Q8A  = (u8*)B2;                                // layer-1 q8 (12.8MB)
    u8* Q8B  = (u8*)B2 + (size_t)Mpad * 128;           // layer-1 q8 #2
    u8* Q8c  = (u8*)CAT1;                              // q8(X1@W2c), 25.6MB
    u16* Yb  = (u16*)((u8*)CAT1 + (size_t)Mpad * 256); // X1@W2b, 51.2MB (fits)
    u16* Ya  = B2;                                     // X1@W2a
    u8* Q8d  = (u8*)X1;                                // X1 dead after gemms
    u16* X2  = CAT1;                                   // final layer-2 out

    // --- CSR build: counting sort (no global atomics) ---
    const int n2 = NB * NC;               // 100096
    countA_kernel<<<NC, 256, 0, stream>>>(dst, Hmat, E, CS, NB);
    scan1_kernel<<<(n2 + 1023) / 1024, 1024, 0, stream>>>(Hmat, Omat, bsum, n2);
    scan2_kernel<<<1, 1024, 0, stream>>>(bsum, (n2 + 1023) / 1024);
    scan3_kernel<<<(n2 + 255) / 256, 256, 0, stream>>>(Omat, bsum, n2, E);
    scatterC_kernel<<<NC, 256, 0, stream>>>(src, dst, Omat, Earr, E, CS, NB);
    fineD_kernel<<<NB, 256, 0, stream>>>(Earr, Omat, colidx, rowptr, normv, N, E, NB);

    // --- weight transposes (bf16) ---
    transpose_cast<<<(CAT * HID + 255) / 256, 256, 0, stream>>>(W1, Wt1, CAT, HID);
    transpose_cast<<<(3 * HID * HID + 255) / 256, 256, 0, stream>>>(
        W2, Wt2f, 3 * HID, HID);          // Wt2f[n*768+k] = W2[k][n]

    // --- layer 1: CAT1 = [bf16(h) | P h | P^2 h]; X1 = relu(CAT1@W1+b1) ---
    int pb = (N + 3) / 4;
    castquant_f32_128<<<pb, 256, 0, stream>>>(h, CAT1, CAT, normv, Q8A, mv, N);
    prop_q8_kernel<4, 1, 1, 0><<<pb, 256, 0, stream>>>(
        Q8A, mv, CAT1 + IN, CAT, rowptr, colidx, normv, N,
        nullptr, nullptr, 0, Q8B, mv2);
    prop_q8_kernel<4, 0, 1, 0><<<pb, 256, 0, stream>>>(
        Q8B, mv2, CAT1 + 2 * IN, CAT, rowptr, colidx, normv, N,
        nullptr, nullptr, 0, nullptr, nullptr);
    const int NJ8 = (Mpad / 128) * 8;     // 6256
    gemm_wave<384, 0><<<NJ8 / 4, 256, 0, stream>>>(
        CAT1, Wt1, 384, b1, X1, nullptr, N, NJ8, 1);

    // --- layer 2 (commuted, fused): ---
    // Q8c = q8(X1@W2c); {Yb,Ya} = X1@{W2b,W2a};
    // Q8d = q8(Yb + P(Q8c)); X2 = relu(Ya + P(Q8d) + b2)
    const int NJQ = Mpad / 16;            // 6256
    gemmq_wave<256><<<NJQ / 4, 256, 0, stream>>>(
        X1, Wt2f + 512, 768, Q8c, mvq, normv, N, NJQ);
    const int NJD = (Mpad / 128) * 16;    // 12512
    gemm_wave<256, 1><<<NJD / 4, 256, 0, stream>>>(
        X1, Wt2f, 768, nullptr, Yb, Ya, N, NJD, 0);
    prop_q8_kernel<8, 1, 0, 1><<<pb, 256, 0, stream>>>(
        Q8c, mvq, nullptr, 256, rowptr, colidx, normv, N,
        Yb, nullptr, 0, Q8d, mv2);
    prop_q8_kernel<8, 0, 1, 1><<<pb, 256, 0, stream>>>(
        Q8d, mv2, X2, 256, rowptr, colidx, normv, N,
        Ya, b2, 1, nullptr, nullptr);

    // --- pool + head ---
    hipMemsetAsync(pooled, 0, (size_t)G * HID * sizeof(float), stream);
    pool_kernel<<<(N + 127) / 128, HID, 0, stream>>>(X2, gid, pooled, N, HID);
    head_kernel<<<G, HID, 0, stream>>>(pooled, Wc, bc, out, HID, C);
}